// Round 3
// baseline (370.449 us; speedup 1.0000x reference)
//
#include <hip/hip_runtime.h>
#include <stdint.h>

#define SEQ  8192
#define NB   128
#define MAXP 4096
#define NTC  512                                  // chain kernel threads
#define WS_STRIDE_U32 2056                        // per-seq starts stride (4112 u16)
#define WS_NEEDED ((size_t)NB * WS_STRIDE_U32 * 4)

__device__ __forceinline__ bool haszero8(uint64_t v) {
    return ((v - 0x0101010101010101ULL) & ~v & 0x8080808080808080ULL) != 0ULL;
}
__device__ __forceinline__ bool distinct8(uint64_t w) {
    uint64_t r1 = (w >> 8)  | (w << 56);
    uint64_t r2 = (w >> 16) | (w << 48);
    uint64_t r3 = (w >> 24) | (w << 40);
    uint64_t r4 = (w >> 32) | (w << 32);
    return !(haszero8(w ^ r1) | haszero8(w ^ r2) | haszero8(w ^ r3) | haszero8(w ^ r4));
}
__device__ __forceinline__ uint32_t pack4(int4 v) {
    return (uint32_t)(v.x & 255) | ((uint32_t)(v.y & 255) << 8) |
           ((uint32_t)(v.z & 255) << 16) | ((uint32_t)(v.w & 255) << 24);
}
// exact jump rule (verified absmax=0 in rounds 1-2)
__device__ __forceinline__ int next_pos(const uint32_t* stopb, int i) {
    int bp = i + 2, w = bp >> 5;
    uint64_t comb = (uint64_t)stopb[w] | ((uint64_t)stopb[w + 1] << 32);
    uint32_t win14 = (uint32_t)(comb >> (bp & 31)) & 0x3FFFu;
    int sz;
    if (win14) sz = 2 + __builtin_ctz(win14);
    else { sz = SEQ - i; if (sz > 16) sz = 16; }
    return i + sz;
}
// 2-bit transfer function f = imgA | (imgB<<1); identity=2, constA=0, swap=1
__device__ __forceinline__ uint32_t compose2(uint32_t f2, uint32_t f1) {  // f2 after f1
    uint32_t a1 = f1 & 1u, b1 = (f1 >> 1) & 1u;
    uint32_t a2 = f2 & 1u, b2 = (f2 >> 1) & 1u;
    return (a1 ? b2 : a2) | ((b1 ? b2 : a2) << 1);
}

// ------------- Kernel 1: patch-start list via stop-index DFA scan -----------------
__global__ __launch_bounds__(NTC) void ep_chain(const int* __restrict__ tokens,
                                                uint32_t* __restrict__ ws_starts) {
    __shared__ uint32_t tok32[2052];
    __shared__ uint16_t stop16[512];
    __shared__ uint32_t stopb[258];
    __shared__ uint16_t qpos[8200];       // sorted stop positions
    __shared__ uint16_t starts_s[4104];
    __shared__ uint32_t off_s[256];       // exclusive stop-count per 32-bit word
    __shared__ int wsum_s[8], tsum_s[8], wsum2_s[8], wmax_s[8];
    __shared__ int S_s[8];                // 0:Nstop 1:k0 2:H 3:irregular 4:P

    const int b = blockIdx.x, tid = threadIdx.x;
    const int lane = tid & 63, wid = tid >> 6;

    // ---- A: load + pack tokens to u8 ----
    {
        const int4* t4 = (const int4*)(tokens + (size_t)b * SEQ);
        #pragma unroll
        for (int k = 0; k < 4; ++k) { int g = k * NTC + tid; tok32[g] = pack4(t4[g]); }
        if (tid < 4) tok32[2048 + tid] = 0u;
        if (tid == 0) S_s[3] = 0;
    }
    __syncthreads();

    // ---- B: stop bits, 16 positions/thread ----
    {
        const int base = tid * 4;
        uint64_t win = (uint64_t)tok32[base] | ((uint64_t)tok32[base + 1] << 32);
        uint32_t bits = 0;
        #pragma unroll
        for (int k = 0; k < 4; ++k) {
            uint32_t nx = tok32[base + 2 + k];
            #pragma unroll
            for (int m = 0; m < 4; ++m) {
                int j = tid * 16 + k * 4 + m;
                if (j <= SEQ - 8 && distinct8(win)) bits |= (1u << (k * 4 + m));
                win = (win >> 8) | ((uint64_t)(nx & 255u) << 56);
                nx >>= 8;
            }
        }
        stop16[tid] = (uint16_t)bits;
    }
    __syncthreads();
    if (tid < 256) stopb[tid] = (uint32_t)stop16[2 * tid] | ((uint32_t)stop16[2 * tid + 1] << 16);
    if (tid < 2) stopb[256 + tid] = 0u;
    __syncthreads();

    // ---- C: stop compaction (prefix sum over word popcounts) ----
    int cw = (tid < 256) ? __popc(stopb[tid]) : 0;
    int cincl = cw;
    #pragma unroll
    for (int d = 1; d < 64; d <<= 1) { int o = __shfl_up(cincl, d); if (lane >= d) cincl += o; }
    if (lane == 63) wsum_s[wid] = cincl;
    __syncthreads();
    int woff = 0;
    for (int w = 0; w < wid; ++w) woff += wsum_s[w];
    int Nstop = 0;
    #pragma unroll
    for (int w = 0; w < 8; ++w) Nstop += wsum_s[w];
    const int myoff = woff + cincl - cw;
    if (tid < 256) {
        off_s[tid] = (uint32_t)myoff;
        uint32_t bits = stopb[tid];
        int p = myoff;
        while (bits) { int j = __builtin_ctz(bits); bits &= bits - 1; qpos[p++] = (uint16_t)(tid * 32 + j); }
    }
    __syncthreads();

    // ---- head walk (thread 0): serial until first stop landing ----
    if (tid == 0) {
        int i = 0, H = 0, k0 = Nstop;
        while (i < SEQ) {
            if ((stopb[i >> 5] >> (i & 31)) & 1u) {
                int w = i >> 5;
                k0 = (int)off_s[w] + __popc(stopb[w] & ((1u << (i & 31)) - 1u));
                break;
            }
            if (H < 4098) starts_s[H] = (uint16_t)i;
            ++H;
            i = next_pos(stopb, i);
        }
        S_s[0] = Nstop; S_s[1] = k0; S_s[2] = H;
    }
    __syncthreads();

    const int k0 = S_s[1], H = S_s[2];
    const int kbeg = tid * 16;

    // ---- D1: per-thread 2-bit transfer compose (+irregular gap check) ----
    uint32_t f = 2u;                               // identity
    #pragma unroll
    for (int m = 0; m < 16; ++m) {
        int k = kbeg + m;
        if (k >= k0 && k < Nstop) {
            int q  = (int)qpos[k];
            int qn = (k + 1 < Nstop) ? (int)qpos[k + 1] : 0x7fff;
            if (k + 1 < Nstop && qn - q >= 16) S_s[3] = 1;   // cap may engage -> fallback
            uint32_t tr = (qn == q + 1) ? 1u : 0u;           // swap : constA
            f = compose2(tr, f);
        }
    }
    // ---- D2: transfer scan across threads ----
    uint32_t fincl = f;
    #pragma unroll
    for (int d = 1; d < 64; d <<= 1) {
        uint32_t o = (uint32_t)__shfl_up((int)fincl, d);
        if (lane >= d) fincl = compose2(fincl, o);
    }
    if (lane == 63) tsum_s[wid] = (int)fincl;
    __syncthreads();
    uint32_t wpref = 2u;
    for (int w = 0; w < wid; ++w) wpref = compose2((uint32_t)tsum_s[w], wpref);
    uint32_t lexcl = (uint32_t)__shfl_up((int)fincl, 1);
    if (lane == 0) lexcl = 2u;
    uint32_t s = compose2(lexcl, wpref) & 1u;      // entry state (0=A lands,1=B skips)

    // ---- D3: replay -> visited bits ----
    uint32_t vis = 0; int c = 0;
    #pragma unroll
    for (int m = 0; m < 16; ++m) {
        int k = kbeg + m;
        if (k >= k0 && k < Nstop) {
            int q  = (int)qpos[k];
            int qn = (k + 1 < Nstop) ? (int)qpos[k + 1] : 0x7fff;
            uint32_t g = (qn == q + 1) ? 1u : 0u;
            if (s == 0u) { vis |= (1u << m); ++c; }
            s = g & (s ^ 1u);
        }
    }
    int lv = vis ? (kbeg + 31 - __clz((int)vis)) : -1;
    #pragma unroll
    for (int d = 32; d >= 1; d >>= 1) { int o = __shfl_xor(lv, d); if (o > lv) lv = o; }
    if (lane == 0) wmax_s[wid] = lv;

    // ---- E: patch-index prefix sum ----
    int pincl = c;
    #pragma unroll
    for (int d = 1; d < 64; d <<= 1) { int o = __shfl_up(pincl, d); if (lane >= d) pincl += o; }
    if (lane == 63) wsum2_s[wid] = pincl;
    __syncthreads();
    int poff = 0;
    for (int w = 0; w < wid; ++w) poff += wsum2_s[w];
    int P2 = 0;
    #pragma unroll
    for (int w = 0; w < 8; ++w) P2 += wsum2_s[w];

    // ---- F: scatter visited stop positions ----
    {
        int p = H + poff + pincl - c;
        uint32_t vv = vis;
        while (vv) {
            int m = __builtin_ctz(vv); vv &= vv - 1;
            if (p < 4098) starts_s[p] = qpos[kbeg + m];
            ++p;
        }
    }
    __syncthreads();

    // ---- T: tail walk + fallback (thread 0) ----
    if (tid == 0) {
        int P = H + P2;
        if (!S_s[3]) {
            if (P2 > 0) {
                int ks = -1;
                #pragma unroll
                for (int w = 0; w < 8; ++w) if (wmax_s[w] > ks) ks = wmax_s[w];
                int i = (int)qpos[ks];
                for (;;) {
                    i = next_pos(stopb, i);
                    if (i >= SEQ) break;
                    if (P < 4098) starts_s[P] = (uint16_t)i;
                    ++P;
                }
            }
        } else {
            // exact serial fallback (never triggers on regular data)
            int i = 0; P = 0;
            while (i < SEQ) {
                if (P < 4098) starts_s[P] = (uint16_t)i;
                ++P;
                i = next_pos(stopb, i);
            }
        }
        S_s[4] = (P > 4097) ? 4097 : P;
    }
    __syncthreads();

    // ---- fill + write to ws ----
    for (int idx = S_s[4] + tid; idx < 4098; idx += NTC) starts_s[idx] = (uint16_t)SEQ;
    __syncthreads();
    {
        const uint32_t* a32 = (const uint32_t*)starts_s;
        uint32_t* dst = ws_starts + (size_t)b * WS_STRIDE_U32;
        for (int w = tid; w < 2049; w += NTC) dst[w] = a32[w];
    }
}

// ------------- Kernel 2: coalesced emission, 8 blocks per sequence ----------------
__global__ __launch_bounds__(256) void ep_emit(const int* __restrict__ tokens,
                                               const uint32_t* __restrict__ ws_starts,
                                               int* __restrict__ out) {
    __shared__ uint16_t s[520];
    __shared__ uint32_t tokw[2052];

    const int b = blockIdx.x >> 3, c = blockIdx.x & 7, tid = threadIdx.x;
    const uint32_t* src = ws_starts + (size_t)b * WS_STRIDE_U32 + c * 256;
    for (int g = tid; g < 258; g += 256) ((uint32_t*)s)[g] = src[g];
    __syncthreads();

    const int base4 = (int)s[0] & ~3;
    const int end   = (int)s[512];
    const int ngrp  = (end - base4 + 3) >> 2;
    const int4* t4 = (const int4*)(tokens + (size_t)b * SEQ);
    const int g0 = base4 >> 2;
    for (int g = tid; g < ngrp; g += 256) tokw[g] = pack4(t4[g0 + g]);
    __syncthreads();

    const uint8_t* tok8 = (const uint8_t*)tokw;
    int* outp = out + (size_t)b * (MAXP * 16) + (size_t)c * (512 * 16);
    const int q = tid & 3;
    #pragma unroll
    for (int it = 0; it < 8; ++it) {
        int p  = it * 64 + (tid >> 2);
        int st = (int)s[p];
        int sz = (int)s[p + 1] - st;
        int off = st - base4 + q * 4;
        int t[4];
        #pragma unroll
        for (int j = 0; j < 4; ++j) {
            int l = q * 4 + j;
            int idx = off + j; if (idx > 8207) idx = 8207;
            t[j] = (l < sz) ? (int)tok8[idx] : 0;
        }
        ((int4*)outp)[p * 4 + q] = make_int4(t[0], t[1], t[2], t[3]);
    }
    int* outm = out + (size_t)NB * MAXP * 16 + (size_t)b * MAXP + c * 512;
    for (int pm = tid; pm < 512; pm += 256)
        outm[pm] = ((int)s[pm] < SEQ) ? 1 : 0;
}

// ------------- Fallback: proven round-1 monolithic kernel -------------------------
__global__ __launch_bounds__(256) void ep_mono(const int* __restrict__ tokens,
                                               int* __restrict__ out) {
    __shared__ uint32_t tok32[2052];
    __shared__ uint32_t stopb[258];
    __shared__ uint8_t  sizes_s[SEQ];
    __shared__ uint16_t f_s[SEQ];
    __shared__ uint16_t starts_s[MAXP + 4];
    __shared__ int      entry_s[130];
    __shared__ int      base_s[130];
    __shared__ int      P_s, nv_s;

    const int b = blockIdx.x, tid = threadIdx.x;
    const int* tseq = tokens + (size_t)b * SEQ;
    {
        const int4* t4 = (const int4*)tseq;
        #pragma unroll
        for (int k = 0; k < 8; ++k) { int g = k * 256 + tid; tok32[g] = pack4(t4[g]); }
        if (tid < 4) tok32[2048 + tid] = 0u;
        if (tid < 2) stopb[256 + tid] = 0u;
    }
    __syncthreads();
    {
        const int base = tid * 8;
        uint64_t win = (uint64_t)tok32[base] | ((uint64_t)tok32[base + 1] << 32);
        uint32_t bits = 0;
        #pragma unroll
        for (int k = 0; k < 8; ++k) {
            uint32_t nx = tok32[base + 2 + k];
            #pragma unroll
            for (int m = 0; m < 4; ++m) {
                int j = tid * 32 + k * 4 + m;
                if (j <= SEQ - 8 && distinct8(win)) bits |= (1u << (k * 4 + m));
                win = (win >> 8) | ((uint64_t)(nx & 255u) << 56);
                nx >>= 8;
            }
        }
        stopb[tid] = bits;
    }
    __syncthreads();
    {
        const int i0 = tid * 32;
        #pragma unroll 4
        for (int m = 0; m < 32; ++m) {
            int i = i0 + m, bp = i + 2, w = bp >> 5;
            uint64_t comb = (uint64_t)stopb[w] | ((uint64_t)stopb[w + 1] << 32);
            uint32_t win14 = (uint32_t)(comb >> (bp & 31)) & 0x3FFFu;
            int sz = win14 ? (2 + __builtin_ctz(win14)) : min(16, SEQ - i);
            sizes_s[i] = (uint8_t)sz;
        }
    }
    __syncthreads();
    if (tid < 128) {
        const int cbase = tid * 64, cend = cbase + 64;
        for (int i = cend - 1; i >= cbase; --i) {
            int j = i + (int)sizes_s[i];
            uint16_t fv;
            if (j >= cend) fv = (uint16_t)((j - cbase) | (1u << 8));
            else { uint16_t fj = f_s[j];
                   fv = (uint16_t)((fj & 255u) | ((uint32_t)((fj >> 8) + 1u) << 8)); }
            f_s[i] = fv;
        }
    }
    __syncthreads();
    if (tid == 0) {
        int i = 0, pidx = 0, m = 0;
        while (i < SEQ) {
            entry_s[m] = i; base_s[m] = pidx;
            uint16_t fv = f_s[i];
            pidx += (int)(fv >> 8);
            i = (i & ~63) + (int)(fv & 255u);
            ++m;
        }
        P_s = pidx; nv_s = m;
        starts_s[pidx] = (uint16_t)SEQ;
    }
    __syncthreads();
    if (tid < nv_s) {
        int i = entry_s[tid], p = base_s[tid];
        const int cend = (i & ~63) + 64;
        while (i < cend) { starts_s[p++] = (uint16_t)i; i += (int)sizes_s[i]; }
    }
    __syncthreads();
    const int P = P_s;
    int* outp = out + (size_t)b * MAXP * 16;
    int* outm = out + (size_t)NB * MAXP * 16 + (size_t)b * MAXP;
    const uint8_t* tok8 = (const uint8_t*)tok32;
    for (int p = tid; p < MAXP; p += 256) {
        int4 o0 = make_int4(0,0,0,0), o1 = o0, o2 = o0, o3 = o0;
        int msk = 0;
        if (p < P) {
            msk = 1;
            int st = (int)starts_s[p];
            int sz = (int)starts_s[p + 1] - st;
            int t[16];
            #pragma unroll
            for (int l = 0; l < 16; ++l) t[l] = (l < sz) ? (int)tok8[st + l] : 0;
            o0 = make_int4(t[0],t[1],t[2],t[3]);   o1 = make_int4(t[4],t[5],t[6],t[7]);
            o2 = make_int4(t[8],t[9],t[10],t[11]); o3 = make_int4(t[12],t[13],t[14],t[15]);
        }
        int4* dst = (int4*)(outp + (size_t)p * 16);
        dst[0] = o0; dst[1] = o1; dst[2] = o2; dst[3] = o3;
        outm[p] = msk;
    }
}

extern "C" void kernel_launch(void* const* d_in, const int* in_sizes, int n_in,
                              void* d_out, int out_size, void* d_ws, size_t ws_size,
                              hipStream_t stream) {
    const int* tokens = (const int*)d_in[0];
    int* out = (int*)d_out;
    if (ws_size >= WS_NEEDED) {
        uint32_t* ws_starts = (uint32_t*)d_ws;
        ep_chain<<<dim3(NB), dim3(NTC), 0, stream>>>(tokens, ws_starts);
        ep_emit<<<dim3(NB * 8), dim3(256), 0, stream>>>(tokens, ws_starts, out);
    } else {
        ep_mono<<<dim3(NB), dim3(256), 0, stream>>>(tokens, out);
    }
}

// Round 4
// 46.026 us; speedup vs baseline: 8.0487x; 8.0487x over previous
//
#include <hip/hip_runtime.h>
#include <stdint.h>

#define SEQ  8192
#define NB   128
#define MAXP 4096
#define NTC  512
#define WS_STRIDE_U32 2056
#define WS_NEEDED ((size_t)NB * WS_STRIDE_U32 * 4)

// ---- 3-state DFA transfer: 0=A(lands on k), 1=B(skips k, lands k+1), 2=DEAD ----
// f encodes images: bits[1:0]=f(A), bits[3:2]=f(B). DEAD always maps to DEAD.
#define ID3 4u   // A->A, B->B
#define CA3 0u   // A->A, B->A
#define SW3 1u   // A->B, B->A
#define EA3 2u   // A->DEAD, B->A

__device__ __forceinline__ uint32_t ap3(uint32_t f, uint32_t s) {
    return (s <= 1u) ? ((f >> (s << 1)) & 3u) : 2u;
}
__device__ __forceinline__ uint32_t comp3(uint32_t f2, uint32_t f1) {  // f2 after f1
    return ap3(f2, f1 & 3u) | (ap3(f2, (f1 >> 2) & 3u) << 2);
}

__device__ __forceinline__ bool haszero8(uint64_t v) {
    return ((v - 0x0101010101010101ULL) & ~v & 0x8080808080808080ULL) != 0ULL;
}
__device__ __forceinline__ bool distinct8(uint64_t w) {
    uint64_t r1 = (w >> 8)  | (w << 56);
    uint64_t r2 = (w >> 16) | (w << 48);
    uint64_t r3 = (w >> 24) | (w << 40);
    uint64_t r4 = (w >> 32) | (w << 32);
    return !(haszero8(w ^ r1) | haszero8(w ^ r2) | haszero8(w ^ r3) | haszero8(w ^ r4));
}
__device__ __forceinline__ uint32_t pack4(int4 v) {
    return (uint32_t)(v.x & 255) | ((uint32_t)(v.y & 255) << 8) |
           ((uint32_t)(v.z & 255) << 16) | ((uint32_t)(v.w & 255) << 24);
}
__device__ __forceinline__ int next_pos(const uint32_t* stopb, int i) {
    int bp = i + 2, w = bp >> 5;
    uint64_t comb = (uint64_t)stopb[w] | ((uint64_t)stopb[w + 1] << 32);
    uint32_t win14 = (uint32_t)(comb >> (bp & 31)) & 0x3FFFu;
    int sz;
    if (win14) sz = 2 + __builtin_ctz(win14);
    else { sz = SEQ - i; if (sz > 16) sz = 16; }
    return i + sz;
}

// ------------- Kernel 1: patch-start list, fully parallel (3-state DFA scan) ------
__global__ __launch_bounds__(NTC) void ep_chain(const int* __restrict__ tokens,
                                                uint32_t* __restrict__ ws_starts) {
    __shared__ uint32_t tok32[2052];
    __shared__ uint16_t stop16[512];
    __shared__ uint32_t stopb[258];
    __shared__ uint16_t qpos[8200];
    __shared__ uint16_t starts_s[4104];
    __shared__ uint32_t off_s[256];
    __shared__ int wsum_s[8];
    __shared__ int tsum_s[8];
    __shared__ int wsum2_s[8];
    __shared__ int S_s[8];              // 0:Nstop 1:k0 2:H 3:breaker 4:P
    // fallback-only arrays
    __shared__ uint8_t  sizes8[SEQ];
    __shared__ uint16_t fdp[SEQ];
    __shared__ int entry_s[132];
    __shared__ int base_s[132];
    __shared__ int nv_s;

    const int b = blockIdx.x, tid = threadIdx.x;
    const int lane = tid & 63, wid = tid >> 6;

    // ---- A: load + pack tokens to u8 ----
    {
        const int4* t4 = (const int4*)(tokens + (size_t)b * SEQ);
        #pragma unroll
        for (int k = 0; k < 4; ++k) { int g = k * NTC + tid; tok32[g] = pack4(t4[g]); }
        if (tid < 4) tok32[2048 + tid] = 0u;
        if (tid == 0) S_s[3] = 0;
    }
    __syncthreads();

    // ---- B: stop bits (exact: entropy>=2.9 <=> full window of 8 distinct bytes) ----
    {
        const int base = tid * 4;
        uint64_t win = (uint64_t)tok32[base] | ((uint64_t)tok32[base + 1] << 32);
        uint32_t bits = 0;
        #pragma unroll
        for (int k = 0; k < 4; ++k) {
            uint32_t nx = tok32[base + 2 + k];
            #pragma unroll
            for (int m = 0; m < 4; ++m) {
                int j = tid * 16 + k * 4 + m;
                if (j <= SEQ - 8 && distinct8(win)) bits |= (1u << (k * 4 + m));
                win = (win >> 8) | ((uint64_t)(nx & 255u) << 56);
                nx >>= 8;
            }
        }
        stop16[tid] = (uint16_t)bits;
    }
    __syncthreads();
    if (tid < 256) stopb[tid] = (uint32_t)stop16[2 * tid] | ((uint32_t)stop16[2 * tid + 1] << 16);
    if (tid < 2) stopb[256 + tid] = 0u;
    __syncthreads();

    // ---- B2: exact breaker detection, from BITMAP only ----
    // breaker iff exists stop q with no stop in [q+2,q+16) and SEQ-q>16
    {
        uint32_t w0 = (tid < 256) ? stopb[tid] : 0u;
        if (w0) {
            uint32_t bb = w0; int any = 0;
            while (bb) {
                int j = (tid << 5) + __builtin_ctz(bb); bb &= bb - 1;
                if (SEQ - j > 16) {
                    int bp = j + 2, w = bp >> 5;
                    uint64_t comb = (uint64_t)stopb[w] | ((uint64_t)stopb[w + 1] << 32);
                    if ((((uint32_t)(comb >> (bp & 31))) & 0x3FFFu) == 0u) any = 1;
                }
            }
            if (any) S_s[3] = 1;
        }
    }

    // ---- C: stop compaction ----
    int cw = (tid < 256) ? __popc(stopb[tid]) : 0;
    int cincl = cw;
    #pragma unroll
    for (int d = 1; d < 64; d <<= 1) { int o = __shfl_up(cincl, d); if (lane >= d) cincl += o; }
    if (lane == 63) wsum_s[wid] = cincl;
    __syncthreads();
    int woff = 0;
    for (int w = 0; w < wid; ++w) woff += wsum_s[w];
    int Nstop = 0;
    #pragma unroll
    for (int w = 0; w < 8; ++w) Nstop += wsum_s[w];
    const int myoff = woff + cincl - cw;
    if (tid < 256) {
        off_s[tid] = (uint32_t)myoff;
        uint32_t bits = stopb[tid];
        int p = myoff;
        while (bits) { int j = __builtin_ctz(bits); bits &= bits - 1; qpos[p++] = (uint16_t)((tid << 5) + j); }
    }
    __syncthreads();

    // ---- C-check: qpos monotonic sanity -> route corruption to cheap fallback ----
    {
        int bad = 0;
        #pragma unroll 4
        for (int m = 0; m < 16; ++m) {
            int k = tid * 16 + m;
            if (k + 1 < Nstop && !((int)qpos[k] < (int)qpos[k + 1])) bad = 1;
        }
        if (bad) S_s[3] = 1;
    }

    // ---- C2: O(1) head (thread 0) ----
    if (tid == 0) {
        int k0, H;
        if (stopb[0] & 1u) { k0 = 0; H = 0; }
        else {
            starts_s[0] = 0; H = 1;
            int j1 = next_pos(stopb, 0);
            if (j1 >= SEQ) k0 = Nstop;                         // single-patch chain
            else if ((stopb[j1 >> 5] >> (j1 & 31)) & 1u) {
                int w = j1 >> 5;
                k0 = (int)off_s[w] + __popc(stopb[w] & ((1u << (j1 & 31)) - 1u));
            } else { k0 = Nstop; S_s[3] = 1; }                 // cap-landed non-stop
        }
        S_s[0] = Nstop; S_s[1] = k0; S_s[2] = H;
    }
    __syncthreads();

    const int brk = S_s[3];
    if (!brk) {
        const int k0 = S_s[1], H = S_s[2];
        const int kbeg = tid * 16;
        // ---- D1: per-thread transfer composition (adjacency from bitmap) ----
        uint32_t f = ID3;
        #pragma unroll
        for (int m = 0; m < 16; ++m) {
            int k = kbeg + m;
            if (k >= k0 && k < Nstop) {
                int q = (int)qpos[k];
                uint32_t adj = (stopb[(q + 1) >> 5] >> ((q + 1) & 31)) & 1u;
                int bp = q + 2, w = bp >> 5;
                uint64_t comb = (uint64_t)stopb[w] | ((uint64_t)stopb[w + 1] << 32);
                uint32_t win14 = (uint32_t)(comb >> (bp & 31)) & 0x3FFFu;
                uint32_t tr = win14 ? (adj ? SW3 : CA3) : EA3;
                f = comp3(tr, f);
            }
        }
        // ---- D2: transfer scan ----
        uint32_t fincl = f;
        #pragma unroll
        for (int d = 1; d < 64; d <<= 1) {
            uint32_t o = (uint32_t)__shfl_up((int)fincl, d);
            if (lane >= d) fincl = comp3(fincl, o);
        }
        if (lane == 63) tsum_s[wid] = (int)fincl;
        __syncthreads();
        uint32_t wpref = ID3;
        for (int w = 0; w < wid; ++w) wpref = comp3((uint32_t)tsum_s[w], wpref);
        uint32_t lexcl = (uint32_t)__shfl_up((int)fincl, 1);
        if (lane == 0) lexcl = ID3;
        uint32_t st = ap3(comp3(lexcl, wpref), 0u);   // state at kbeg
        // ---- D3: replay -> visited bits ----
        uint32_t vis = 0; int c = 0;
        #pragma unroll
        for (int m = 0; m < 16; ++m) {
            int k = kbeg + m;
            if (k >= k0 && k < Nstop) {
                int q = (int)qpos[k];
                uint32_t adj = (stopb[(q + 1) >> 5] >> ((q + 1) & 31)) & 1u;
                int bp = q + 2, w = bp >> 5;
                uint64_t comb = (uint64_t)stopb[w] | ((uint64_t)stopb[w + 1] << 32);
                uint32_t win14 = (uint32_t)(comb >> (bp & 31)) & 0x3FFFu;
                uint32_t tr = win14 ? (adj ? SW3 : CA3) : EA3;
                if (st == 0u) { vis |= (1u << m); ++c; }
                st = ap3(tr, st);
            }
        }
        // ---- E: patch-index prefix sum ----
        int pincl = c;
        #pragma unroll
        for (int d = 1; d < 64; d <<= 1) { int o = __shfl_up(pincl, d); if (lane >= d) pincl += o; }
        if (lane == 63) wsum2_s[wid] = pincl;
        __syncthreads();
        int poff = 0;
        for (int w = 0; w < wid; ++w) poff += wsum2_s[w];
        int P2 = 0;
        #pragma unroll
        for (int w = 0; w < 8; ++w) P2 += wsum2_s[w];
        // ---- F: scatter (no tail walk needed: END state covers sequence end) ----
        {
            int p = H + poff + pincl - c;
            uint32_t vv = vis;
            while (vv) {
                int m = __builtin_ctz(vv); vv &= vv - 1;
                if (p < 4098) starts_s[p] = qpos[kbeg + m];
                ++p;
            }
        }
        if (tid == 0) { int P = H + P2; S_s[4] = (P > 4097) ? 4097 : P; }
        __syncthreads();
    } else {
        // ---- fallback: round-1 chunk-DP (exact, parallel, ~8us worst case) ----
        #pragma unroll 4
        for (int m = 0; m < 16; ++m) {
            int i = tid * 16 + m;
            int bp = i + 2, w = bp >> 5;
            uint64_t comb = (uint64_t)stopb[w] | ((uint64_t)stopb[w + 1] << 32);
            uint32_t win14 = (uint32_t)(comb >> (bp & 31)) & 0x3FFFu;
            int sz = win14 ? (2 + __builtin_ctz(win14)) : min(16, SEQ - i);
            sizes8[i] = (uint8_t)sz;
        }
        __syncthreads();
        if (tid < 128) {
            const int cbase = tid * 64, cend = cbase + 64;
            for (int i = cend - 1; i >= cbase; --i) {
                int j = i + (int)sizes8[i];
                uint16_t fv;
                if (j >= cend) fv = (uint16_t)((j - cbase) | (1u << 8));
                else { uint16_t fj = fdp[j];
                       fv = (uint16_t)((fj & 255u) | ((uint32_t)((fj >> 8) + 1u) << 8)); }
                fdp[i] = fv;
            }
        }
        __syncthreads();
        if (tid == 0) {
            int i = 0, pidx = 0, m = 0;
            while (i < SEQ) {
                entry_s[m] = i; base_s[m] = pidx;
                uint16_t fv = fdp[i];
                pidx += (int)(fv >> 8);
                i = (i & ~63) + (int)(fv & 255u);
                ++m;
            }
            S_s[4] = (pidx > 4097) ? 4097 : pidx;
            nv_s = m;
        }
        __syncthreads();
        if (tid < nv_s) {
            int i = entry_s[tid], p = base_s[tid];
            const int cend = (i & ~63) + 64;
            while (i < cend && p < 4098) { starts_s[p++] = (uint16_t)i; i += (int)sizes8[i]; }
        }
        __syncthreads();
    }

    // ---- fill sentinel region + write to workspace ----
    for (int idx = S_s[4] + tid; idx < 4098; idx += NTC) starts_s[idx] = (uint16_t)SEQ;
    __syncthreads();
    {
        const uint32_t* a32 = (const uint32_t*)starts_s;
        uint32_t* dst = ws_starts + (size_t)b * WS_STRIDE_U32;
        for (int w = tid; w < 2049; w += NTC) dst[w] = a32[w];
    }
}

// ------------- Kernel 2: coalesced emission, 8 blocks per sequence ----------------
__global__ __launch_bounds__(256) void ep_emit(const int* __restrict__ tokens,
                                               const uint32_t* __restrict__ ws_starts,
                                               int* __restrict__ out) {
    __shared__ uint16_t s[520];
    __shared__ uint32_t tokw[2052];

    const int b = blockIdx.x >> 3, c = blockIdx.x & 7, tid = threadIdx.x;
    const uint32_t* src = ws_starts + (size_t)b * WS_STRIDE_U32 + c * 256;
    for (int g = tid; g < 258; g += 256) ((uint32_t*)s)[g] = src[g];
    __syncthreads();

    const int base4 = (int)s[0] & ~3;
    const int end   = (int)s[512];
    const int ngrp  = (end - base4 + 3) >> 2;
    const int4* t4 = (const int4*)(tokens + (size_t)b * SEQ);
    const int g0 = base4 >> 2;
    for (int g = tid; g < ngrp; g += 256) tokw[g] = pack4(t4[g0 + g]);
    __syncthreads();

    const uint8_t* tok8 = (const uint8_t*)tokw;
    int* outp = out + (size_t)b * (MAXP * 16) + (size_t)c * (512 * 16);
    const int q = tid & 3;
    #pragma unroll
    for (int it = 0; it < 8; ++it) {
        int p  = it * 64 + (tid >> 2);
        int st = (int)s[p];
        int sz = (int)s[p + 1] - st;
        int off = st - base4 + q * 4;
        int t[4];
        #pragma unroll
        for (int j = 0; j < 4; ++j) {
            int l = q * 4 + j;
            int idx = off + j; if (idx > 8207) idx = 8207;
            t[j] = (l < sz) ? (int)tok8[idx] : 0;
        }
        ((int4*)outp)[p * 4 + q] = make_int4(t[0], t[1], t[2], t[3]);
    }
    int* outm = out + (size_t)NB * MAXP * 16 + (size_t)b * MAXP + c * 512;
    for (int pm = tid; pm < 512; pm += 256)
        outm[pm] = ((int)s[pm] < SEQ) ? 1 : 0;
}

// ------------- Fallback: proven round-1 monolithic kernel -------------------------
__global__ __launch_bounds__(256) void ep_mono(const int* __restrict__ tokens,
                                               int* __restrict__ out) {
    __shared__ uint32_t tok32[2052];
    __shared__ uint32_t stopb[258];
    __shared__ uint8_t  sizes_s[SEQ];
    __shared__ uint16_t f_s[SEQ];
    __shared__ uint16_t starts_s[MAXP + 4];
    __shared__ int      entry_s[130];
    __shared__ int      base_s[130];
    __shared__ int      P_s, nv_s;

    const int b = blockIdx.x, tid = threadIdx.x;
    const int* tseq = tokens + (size_t)b * SEQ;
    {
        const int4* t4 = (const int4*)tseq;
        #pragma unroll
        for (int k = 0; k < 8; ++k) { int g = k * 256 + tid; tok32[g] = pack4(t4[g]); }
        if (tid < 4) tok32[2048 + tid] = 0u;
        if (tid < 2) stopb[256 + tid] = 0u;
    }
    __syncthreads();
    {
        const int base = tid * 8;
        uint64_t win = (uint64_t)tok32[base] | ((uint64_t)tok32[base + 1] << 32);
        uint32_t bits = 0;
        #pragma unroll
        for (int k = 0; k < 8; ++k) {
            uint32_t nx = tok32[base + 2 + k];
            #pragma unroll
            for (int m = 0; m < 4; ++m) {
                int j = tid * 32 + k * 4 + m;
                if (j <= SEQ - 8 && distinct8(win)) bits |= (1u << (k * 4 + m));
                win = (win >> 8) | ((uint64_t)(nx & 255u) << 56);
                nx >>= 8;
            }
        }
        stopb[tid] = bits;
    }
    __syncthreads();
    {
        const int i0 = tid * 32;
        #pragma unroll 4
        for (int m = 0; m < 32; ++m) {
            int i = i0 + m, bp = i + 2, w = bp >> 5;
            uint64_t comb = (uint64_t)stopb[w] | ((uint64_t)stopb[w + 1] << 32);
            uint32_t win14 = (uint32_t)(comb >> (bp & 31)) & 0x3FFFu;
            int sz = win14 ? (2 + __builtin_ctz(win14)) : min(16, SEQ - i);
            sizes_s[i] = (uint8_t)sz;
        }
    }
    __syncthreads();
    if (tid < 128) {
        const int cbase = tid * 64, cend = cbase + 64;
        for (int i = cend - 1; i >= cbase; --i) {
            int j = i + (int)sizes_s[i];
            uint16_t fv;
            if (j >= cend) fv = (uint16_t)((j - cbase) | (1u << 8));
            else { uint16_t fj = f_s[j];
                   fv = (uint16_t)((fj & 255u) | ((uint32_t)((fj >> 8) + 1u) << 8)); }
            f_s[i] = fv;
        }
    }
    __syncthreads();
    if (tid == 0) {
        int i = 0, pidx = 0, m = 0;
        while (i < SEQ) {
            entry_s[m] = i; base_s[m] = pidx;
            uint16_t fv = f_s[i];
            pidx += (int)(fv >> 8);
            i = (i & ~63) + (int)(fv & 255u);
            ++m;
        }
        P_s = pidx; nv_s = m;
        starts_s[pidx] = (uint16_t)SEQ;
    }
    __syncthreads();
    if (tid < nv_s) {
        int i = entry_s[tid], p = base_s[tid];
        const int cend = (i & ~63) + 64;
        while (i < cend) { starts_s[p++] = (uint16_t)i; i += (int)sizes_s[i]; }
    }
    __syncthreads();
    const int P = P_s;
    int* outp = out + (size_t)b * MAXP * 16;
    int* outm = out + (size_t)NB * MAXP * 16 + (size_t)b * MAXP;
    const uint8_t* tok8 = (const uint8_t*)tok32;
    for (int p = tid; p < MAXP; p += 256) {
        int4 o0 = make_int4(0,0,0,0), o1 = o0, o2 = o0, o3 = o0;
        int msk = 0;
        if (p < P) {
            msk = 1;
            int st = (int)starts_s[p];
            int sz = (int)starts_s[p + 1] - st;
            int t[16];
            #pragma unroll
            for (int l = 0; l < 16; ++l) t[l] = (l < sz) ? (int)tok8[st + l] : 0;
            o0 = make_int4(t[0],t[1],t[2],t[3]);   o1 = make_int4(t[4],t[5],t[6],t[7]);
            o2 = make_int4(t[8],t[9],t[10],t[11]); o3 = make_int4(t[12],t[13],t[14],t[15]);
        }
        int4* dst = (int4*)(outp + (size_t)p * 16);
        dst[0] = o0; dst[1] = o1; dst[2] = o2; dst[3] = o3;
        outm[p] = msk;
    }
}

extern "C" void kernel_launch(void* const* d_in, const int* in_sizes, int n_in,
                              void* d_out, int out_size, void* d_ws, size_t ws_size,
                              hipStream_t stream) {
    const int* tokens = (const int*)d_in[0];
    int* out = (int*)d_out;
    if (ws_size >= WS_NEEDED) {
        uint32_t* ws_starts = (uint32_t*)d_ws;
        ep_chain<<<dim3(NB), dim3(NTC), 0, stream>>>(tokens, ws_starts);
        ep_emit<<<dim3(NB * 8), dim3(256), 0, stream>>>(tokens, ws_starts, out);
    } else {
        ep_mono<<<dim3(NB), dim3(256), 0, stream>>>(tokens, out);
    }
}

// Round 5
// 27.944 us; speedup vs baseline: 13.2569x; 1.6471x over previous
//
#include <hip/hip_runtime.h>
#include <stdint.h>

#define SEQ  8192
#define NB   128
#define MAXP 4096
#define NTC  512
#define NCH  256     // chunks per sequence
#define CW   32      // chunk width
#define WS_STRIDE_U32 2056
#define WS_NEEDED ((size_t)NB * WS_STRIDE_U32 * 4)

__device__ __forceinline__ bool haszero8(uint64_t v) {
    return ((v - 0x0101010101010101ULL) & ~v & 0x8080808080808080ULL) != 0ULL;
}
__device__ __forceinline__ bool distinct8(uint64_t w) {
    uint64_t r1 = (w >> 8)  | (w << 56);
    uint64_t r2 = (w >> 16) | (w << 48);
    uint64_t r3 = (w >> 24) | (w << 40);
    uint64_t r4 = (w >> 32) | (w << 32);
    return !(haszero8(w ^ r1) | haszero8(w ^ r2) | haszero8(w ^ r3) | haszero8(w ^ r4));
}
__device__ __forceinline__ uint32_t pack4(int4 v) {
    return (uint32_t)(v.x & 255) | ((uint32_t)(v.y & 255) << 8) |
           ((uint32_t)(v.z & 255) << 16) | ((uint32_t)(v.w & 255) << 24);
}
// select byte b (0..15) of 16-byte fn held in uint4 (static indexing only)
__device__ __forceinline__ uint32_t bsel16(uint4 f, uint32_t b) {
    uint32_t w01 = (b & 4u) ? f.y : f.x;
    uint32_t w23 = (b & 4u) ? f.w : f.z;
    uint32_t w   = (b & 8u) ? w23 : w01;
    return (w >> ((b & 3u) << 3)) & 255u;
}
// r.byte[i] = g.byte[f.byte[i]], all byte values in [0,16)
__device__ __forceinline__ uint4 comp16(uint4 g, uint4 f) {
    uint4 r;
#if __has_builtin(__builtin_amdgcn_perm)
    #define C16W(fw, out) do { \
        uint32_t sel = (fw) & 0x07070707u; \
        uint32_t lo = __builtin_amdgcn_perm(g.y, g.x, sel); \
        uint32_t hi = __builtin_amdgcn_perm(g.w, g.z, sel); \
        uint32_t m = ((fw) & 0x08080808u) >> 3; m = (m << 8) - m; \
        out = (lo & ~m) | (hi & m); } while (0)
    C16W(f.x, r.x); C16W(f.y, r.y); C16W(f.z, r.z); C16W(f.w, r.w);
    #undef C16W
#else
    #define C16B(fw, out) do { uint32_t o = 0; \
        o |= bsel16(g, (fw) & 15u); \
        o |= bsel16(g, ((fw) >> 8) & 15u) << 8; \
        o |= bsel16(g, ((fw) >> 16) & 15u) << 16; \
        o |= bsel16(g, ((fw) >> 24) & 15u) << 24; \
        out = o; } while (0)
    C16B(f.x, r.x); C16B(f.y, r.y); C16B(f.z, r.z); C16B(f.w, r.w);
    #undef C16B
#endif
    return r;
}

// ---------------- Kernel 1: chunk-transfer-function scan (exact, no fallback) -----
__global__ __launch_bounds__(NTC) void ep_chain(const int* __restrict__ tokens,
                                                uint32_t* __restrict__ ws_starts) {
    __shared__ uint32_t tok32[2052];
    __shared__ uint16_t stop16[512];
    __shared__ uint32_t stopb[258];
    __shared__ uint8_t  sizes8[SEQ];
    __shared__ uint32_t exitf32[NCH * 4];   // per chunk: 16 exit bytes
    __shared__ uint32_t cntf32[NCH * 4];    // per chunk: 16 count bytes
    __shared__ uint8_t  entry_s[NCH];
    __shared__ uint16_t pbase_s[NCH];
    __shared__ uint16_t starts_s[4100];
    __shared__ int wsum_s[8];
    __shared__ int S_s[4];                  // 0: total P

    const int b = blockIdx.x, tid = threadIdx.x;
    const int lane = tid & 63, wid = tid >> 6;

    // ---- A: coalesced load, pack tokens to u8 ----
    {
        const int4* t4 = (const int4*)(tokens + (size_t)b * SEQ);
        #pragma unroll
        for (int k = 0; k < 4; ++k) { int g = k * NTC + tid; tok32[g] = pack4(t4[g]); }
        if (tid < 4) tok32[2048 + tid] = 0u;
    }
    __syncthreads();

    // ---- B: stop bits (exact: ent>=2.9 <=> full 8-window all-distinct) ----
    {
        const int base = tid * 4;
        uint64_t win = (uint64_t)tok32[base] | ((uint64_t)tok32[base + 1] << 32);
        uint32_t bits = 0;
        #pragma unroll
        for (int k = 0; k < 4; ++k) {
            uint32_t nx = tok32[base + 2 + k];
            #pragma unroll
            for (int m = 0; m < 4; ++m) {
                int j = tid * 16 + k * 4 + m;
                if (j <= SEQ - 8 && distinct8(win)) bits |= (1u << (k * 4 + m));
                win = (win >> 8) | ((uint64_t)(nx & 255u) << 56);
                nx >>= 8;
            }
        }
        stop16[tid] = (uint16_t)bits;
    }
    __syncthreads();
    if (tid < 256) stopb[tid] = (uint32_t)stop16[2 * tid] | ((uint32_t)stop16[2 * tid + 1] << 16);
    if (tid < 2) stopb[256 + tid] = 0u;
    __syncthreads();

    // ---- Bs: sizes8[i] (proven formula; caps & tail handled exactly) ----
    {
        #pragma unroll 4
        for (int m = 0; m < 16; ++m) {
            int i = tid * 16 + m;
            int bp = i + 2, w = bp >> 5;
            uint64_t comb = (uint64_t)stopb[w] | ((uint64_t)stopb[w + 1] << 32);
            uint32_t win14 = (uint32_t)(comb >> (bp & 31)) & 0x3FFFu;
            int sz = win14 ? (2 + __builtin_ctz(win14)) : min(16, SEQ - i);
            sizes8[i] = (uint8_t)sz;
        }
    }
    __syncthreads();

    // ---- T: build chunk transfer functions (8 interleaved walks per thread) ----
    {
        const int c = tid >> 1, e0 = (tid & 1) << 3;
        const int cb = c * CW, lim = cb + CW;
        int pp[8], cc[8];
        #pragma unroll
        for (int k = 0; k < 8; ++k) { pp[k] = cb + e0 + k; cc[k] = 0; }
        for (int it = 0; it < 17; ++it) {
            bool any = false;
            #pragma unroll
            for (int k = 0; k < 8; ++k) {
                bool a = pp[k] < lim;
                int sp = a ? pp[k] : cb;
                int s = (int)sizes8[sp];
                if (a) { cc[k] += 1; pp[k] += s; any = true; }
            }
            if (!any) break;
        }
        uint32_t xw0 = 0, xw1 = 0, cw0 = 0, cw1 = 0;
        #pragma unroll
        for (int k = 0; k < 4; ++k) {
            xw0 |= (uint32_t)(pp[k] - lim) << (k * 8);
            cw0 |= (uint32_t)cc[k] << (k * 8);
            xw1 |= (uint32_t)(pp[k + 4] - lim) << (k * 8);
            cw1 |= (uint32_t)cc[k + 4] << (k * 8);
        }
        int wb = (c << 2) + ((tid & 1) << 1);
        exitf32[wb] = xw0; exitf32[wb + 1] = xw1;
        cntf32[wb]  = cw0; cntf32[wb + 1]  = cw1;
    }
    __syncthreads();

    // ---- S: wave-0 scan of exit functions -> entry offset of every chunk ----
    if (tid < 64) {
        const uint4* xf4 = (const uint4*)exitf32;
        uint4 f0 = xf4[tid * 4], f1 = xf4[tid * 4 + 1],
              f2 = xf4[tid * 4 + 2], f3 = xf4[tid * 4 + 3];
        uint4 g = comp16(f1, f0);
        g = comp16(f2, g);
        g = comp16(f3, g);                       // inclusive over 4-chunk group
        #pragma unroll
        for (int d = 1; d < 64; d <<= 1) {
            uint4 o;
            o.x = (uint32_t)__shfl_up((int)g.x, d);
            o.y = (uint32_t)__shfl_up((int)g.y, d);
            o.z = (uint32_t)__shfl_up((int)g.z, d);
            o.w = (uint32_t)__shfl_up((int)g.w, d);
            if (tid >= d) g = comp16(g, o);
        }
        uint4 E;
        E.x = (uint32_t)__shfl_up((int)g.x, 1);
        E.y = (uint32_t)__shfl_up((int)g.y, 1);
        E.z = (uint32_t)__shfl_up((int)g.z, 1);
        E.w = (uint32_t)__shfl_up((int)g.w, 1);
        if (tid == 0) E = make_uint4(0x03020100u, 0x07060504u, 0x0B0A0908u, 0x0F0E0D0Cu);
        uint32_t e0 = E.x & 255u;                // entry of chunk 4*tid
        uint32_t e1 = bsel16(f0, e0);
        uint32_t e2 = bsel16(f1, e1);
        uint32_t e3 = bsel16(f2, e2);
        entry_s[tid * 4 + 0] = (uint8_t)e0;
        entry_s[tid * 4 + 1] = (uint8_t)e1;
        entry_s[tid * 4 + 2] = (uint8_t)e2;
        entry_s[tid * 4 + 3] = (uint8_t)e3;
    }
    __syncthreads();

    // ---- C2: per-chunk count at actual entry + prefix sum -> patch bases ----
    {
        int cnt = 0;
        if (tid < NCH) cnt = (int)((const uint8_t*)cntf32)[tid * 16 + (int)entry_s[tid]];
        int inc = cnt;
        #pragma unroll
        for (int d = 1; d < 64; d <<= 1) { int o = __shfl_up(inc, d); if (lane >= d) inc += o; }
        if (lane == 63) wsum_s[wid] = inc;
        __syncthreads();
        int off = 0;
        for (int w = 0; w < wid; ++w) off += wsum_s[w];
        if (tid < NCH) pbase_s[tid] = (uint16_t)(off + inc - cnt);
        if (tid == NCH - 1) S_s[0] = off + inc;   // total P
    }
    __syncthreads();

    // ---- X: per-chunk expansion (every chunk entered exactly once) ----
    if (tid < NCH) {
        int pb = (int)pbase_s[tid];
        int p = tid * CW + (int)entry_s[tid];
        const int lim = tid * CW + CW;
        while (p < lim) {
            starts_s[pb++] = (uint16_t)p;
            p += (int)sizes8[p];
        }
    }
    __syncthreads();

    // ---- sentinel fill + write to workspace ----
    {
        const int P = S_s[0];
        for (int i = P + tid; i < 4098; i += NTC) starts_s[i] = (uint16_t)SEQ;
    }
    __syncthreads();
    {
        const uint32_t* a32 = (const uint32_t*)starts_s;
        uint32_t* dst = ws_starts + (size_t)b * WS_STRIDE_U32;
        for (int w = tid; w < 2049; w += NTC) dst[w] = a32[w];
    }
}

// ---------------- Kernel 2: coalesced emission, 16 blocks per sequence ------------
__global__ __launch_bounds__(256) void ep_emit(const int* __restrict__ tokens,
                                               const uint32_t* __restrict__ ws_starts,
                                               int* __restrict__ out) {
    __shared__ uint16_t s[260];         // 257 starts used
    __shared__ uint32_t tokw[1036];     // token span as u8 (span <= 4099 tokens)

    const int b = blockIdx.x >> 4, c = blockIdx.x & 15, tid = threadIdx.x;
    const uint32_t* src = ws_starts + (size_t)b * WS_STRIDE_U32 + c * 128;
    if (tid < 129) ((uint32_t*)s)[tid] = src[tid];
    __syncthreads();

    const int base4 = (int)s[0] & ~3;
    const int end   = (int)s[256];
    int ngrp = (end - base4 + 3) >> 2;
    if (ngrp > 1032) ngrp = 1032;       // provably <=1025; defensive clamp
    const int4* t4 = (const int4*)(tokens + (size_t)b * SEQ);
    const int g0 = base4 >> 2;
    for (int g = tid; g < ngrp; g += 256) tokw[g] = pack4(t4[g0 + g]);
    __syncthreads();

    const uint8_t* tok8 = (const uint8_t*)tokw;
    int* outp = out + (size_t)b * (MAXP * 16) + (size_t)c * (256 * 16);
    const int q = tid & 3;
    #pragma unroll
    for (int it = 0; it < 4; ++it) {
        int p  = it * 64 + (tid >> 2);
        int st = (int)s[p];
        int sz = (int)s[p + 1] - st;
        int off = st - base4 + q * 4;
        int t[4];
        #pragma unroll
        for (int j = 0; j < 4; ++j) {
            int l = q * 4 + j;
            int idx = off + j; if (idx > 4143) idx = 4143;
            t[j] = (l < sz) ? (int)tok8[idx] : 0;
        }
        ((int4*)outp)[p * 4 + q] = make_int4(t[0], t[1], t[2], t[3]);
    }
    int* outm = out + (size_t)NB * MAXP * 16 + (size_t)b * MAXP + c * 256;
    outm[tid] = ((int)s[tid] < SEQ) ? 1 : 0;
}

// ---------------- Fallback (ws too small): proven round-1 monolithic --------------
__global__ __launch_bounds__(256) void ep_mono(const int* __restrict__ tokens,
                                               int* __restrict__ out) {
    __shared__ uint32_t tok32[2052];
    __shared__ uint32_t stopb[258];
    __shared__ uint8_t  sizes_s[SEQ];
    __shared__ uint16_t f_s[SEQ];
    __shared__ uint16_t starts_s[MAXP + 4];
    __shared__ int      entry_s[130];
    __shared__ int      base_s[130];
    __shared__ int      P_s, nv_s;

    const int b = blockIdx.x, tid = threadIdx.x;
    const int* tseq = tokens + (size_t)b * SEQ;
    {
        const int4* t4 = (const int4*)tseq;
        #pragma unroll
        for (int k = 0; k < 8; ++k) { int g = k * 256 + tid; tok32[g] = pack4(t4[g]); }
        if (tid < 4) tok32[2048 + tid] = 0u;
        if (tid < 2) stopb[256 + tid] = 0u;
    }
    __syncthreads();
    {
        const int base = tid * 8;
        uint64_t win = (uint64_t)tok32[base] | ((uint64_t)tok32[base + 1] << 32);
        uint32_t bits = 0;
        #pragma unroll
        for (int k = 0; k < 8; ++k) {
            uint32_t nx = tok32[base + 2 + k];
            #pragma unroll
            for (int m = 0; m < 4; ++m) {
                int j = tid * 32 + k * 4 + m;
                if (j <= SEQ - 8 && distinct8(win)) bits |= (1u << (k * 4 + m));
                win = (win >> 8) | ((uint64_t)(nx & 255u) << 56);
                nx >>= 8;
            }
        }
        stopb[tid] = bits;
    }
    __syncthreads();
    {
        const int i0 = tid * 32;
        #pragma unroll 4
        for (int m = 0; m < 32; ++m) {
            int i = i0 + m, bp = i + 2, w = bp >> 5;
            uint64_t comb = (uint64_t)stopb[w] | ((uint64_t)stopb[w + 1] << 32);
            uint32_t win14 = (uint32_t)(comb >> (bp & 31)) & 0x3FFFu;
            int sz = win14 ? (2 + __builtin_ctz(win14)) : min(16, SEQ - i);
            sizes_s[i] = (uint8_t)sz;
        }
    }
    __syncthreads();
    if (tid < 128) {
        const int cbase = tid * 64, cend = cbase + 64;
        for (int i = cend - 1; i >= cbase; --i) {
            int j = i + (int)sizes_s[i];
            uint16_t fv;
            if (j >= cend) fv = (uint16_t)((j - cbase) | (1u << 8));
            else { uint16_t fj = f_s[j];
                   fv = (uint16_t)((fj & 255u) | ((uint32_t)((fj >> 8) + 1u) << 8)); }
            f_s[i] = fv;
        }
    }
    __syncthreads();
    if (tid == 0) {
        int i = 0, pidx = 0, m = 0;
        while (i < SEQ) {
            entry_s[m] = i; base_s[m] = pidx;
            uint16_t fv = f_s[i];
            pidx += (int)(fv >> 8);
            i = (i & ~63) + (int)(fv & 255u);
            ++m;
        }
        P_s = pidx; nv_s = m;
        starts_s[pidx] = (uint16_t)SEQ;
    }
    __syncthreads();
    if (tid < nv_s) {
        int i = entry_s[tid], p = base_s[tid];
        const int cend = (i & ~63) + 64;
        while (i < cend) { starts_s[p++] = (uint16_t)i; i += (int)sizes_s[i]; }
    }
    __syncthreads();
    const int P = P_s;
    int* outp = out + (size_t)b * MAXP * 16;
    int* outm = out + (size_t)NB * MAXP * 16 + (size_t)b * MAXP;
    const uint8_t* tok8 = (const uint8_t*)tok32;
    for (int p = tid; p < MAXP; p += 256) {
        int4 o0 = make_int4(0,0,0,0), o1 = o0, o2 = o0, o3 = o0;
        int msk = 0;
        if (p < P) {
            msk = 1;
            int st = (int)starts_s[p];
            int sz = (int)starts_s[p + 1] - st;
            int t[16];
            #pragma unroll
            for (int l = 0; l < 16; ++l) t[l] = (l < sz) ? (int)tok8[st + l] : 0;
            o0 = make_int4(t[0],t[1],t[2],t[3]);   o1 = make_int4(t[4],t[5],t[6],t[7]);
            o2 = make_int4(t[8],t[9],t[10],t[11]); o3 = make_int4(t[12],t[13],t[14],t[15]);
        }
        int4* dst = (int4*)(outp + (size_t)p * 16);
        dst[0] = o0; dst[1] = o1; dst[2] = o2; dst[3] = o3;
        outm[p] = msk;
    }
}

extern "C" void kernel_launch(void* const* d_in, const int* in_sizes, int n_in,
                              void* d_out, int out_size, void* d_ws, size_t ws_size,
                              hipStream_t stream) {
    const int* tokens = (const int*)d_in[0];
    int* out = (int*)d_out;
    if (ws_size >= WS_NEEDED) {
        uint32_t* ws_starts = (uint32_t*)d_ws;
        ep_chain<<<dim3(NB), dim3(NTC), 0, stream>>>(tokens, ws_starts);
        ep_emit<<<dim3(NB * 16), dim3(256), 0, stream>>>(tokens, ws_starts, out);
    } else {
        ep_mono<<<dim3(NB), dim3(256), 0, stream>>>(tokens, out);
    }
}